// Round 1
// baseline (363.929 us; speedup 1.0000x reference)
//
#include <hip/hip_runtime.h>
#include <cstdint>

typedef unsigned short u16;
typedef __attribute__((ext_vector_type(8))) short bf16x8;
typedef __attribute__((ext_vector_type(4))) float f32x4;

__device__ __forceinline__ u16 f2b(float f) {
  union { float f; unsigned u; } x; x.f = f;
  unsigned r = x.u + 0x7fffu + ((x.u >> 16) & 1u);   // RNE
  return (u16)(r >> 16);
}
__device__ __forceinline__ float b2f(u16 u) {
  union { unsigned u; float f; } x; x.u = ((unsigned)u) << 16;
  return x.f;
}

__device__ __forceinline__ void gld16(void* lds, const void* g) {
  __builtin_amdgcn_global_load_lds((const __attribute__((address_space(1))) void*)g,
                                   (__attribute__((address_space(3))) void*)lds, 16, 0, 0);
}

// ---------------------------------------------------------------------------
// w_qkv fp32 -> bf16 (same layout)
// ---------------------------------------------------------------------------
__global__ __launch_bounds__(256) void convert_w(const float* __restrict__ w,
                                                 u16* __restrict__ o) {
  const int i = (blockIdx.x * 256 + threadIdx.x) * 4;
  const float4 v = *(const float4*)(w + i);
  ushort4 r;
  r.x = f2b(v.x); r.y = f2b(v.y); r.z = f2b(v.z); r.w = f2b(v.w);
  *(ushort4*)(o + i) = r;
}

// ---------------------------------------------------------------------------
// Transpose [b][512][4096] -> [b][4096][512] with bf16 output.
// MODE 0: fp32 input, MODE 1: bf16 input. 64x64 tile, XOR-swizzled LDS.
// ---------------------------------------------------------------------------
__device__ __forceinline__ int sw_idx(int n, int c) {
  return n * 64 + ((((c >> 2) ^ (n >> 2)) & 15) << 2) + (c & 3);
}

template <int MODE>
__global__ __launch_bounds__(256) void transpose_to_bf16(const void* __restrict__ src,
                                                         u16* __restrict__ dst) {
  __shared__ u16 t[64 * 64];
  const int tid = threadIdx.x;
  const int b = blockIdx.z;
  const int n0 = blockIdx.x * 64;
  const int c0 = blockIdx.y * 64;
  const int nl = (tid & 15) * 4;
  const int cl = tid >> 4;
#pragma unroll
  for (int r = 0; r < 4; r++) {
    const int c = cl + r * 16;
    if (MODE == 0) {
      const float* sp = (const float*)src + ((long)b * 512 + c0 + c) * 4096 + n0 + nl;
      const float4 v = *(const float4*)sp;
      t[sw_idx(nl + 0, c)] = f2b(v.x);
      t[sw_idx(nl + 1, c)] = f2b(v.y);
      t[sw_idx(nl + 2, c)] = f2b(v.z);
      t[sw_idx(nl + 3, c)] = f2b(v.w);
    } else {
      const u16* sp = (const u16*)src + ((long)b * 512 + c0 + c) * 4096 + n0 + nl;
      const ushort4 v = *(const ushort4*)sp;
      t[sw_idx(nl + 0, c)] = v.x;
      t[sw_idx(nl + 1, c)] = v.y;
      t[sw_idx(nl + 2, c)] = v.z;
      t[sw_idx(nl + 3, c)] = v.w;
    }
  }
  __syncthreads();
  const int cw = (tid & 15) * 4;
#pragma unroll
  for (int r = 0; r < 4; r++) {
    const int n = cl + r * 16;
    const u16* tp = &t[sw_idx(n, cw)];
    ushort4 o;
    o.x = tp[0]; o.y = tp[1]; o.z = tp[2]; o.w = tp[3];
    *(ushort4*)(dst + ((long)b * 4096 + n0 + n) * 512 + c0 + cw) = o;
  }
}

// ---------------------------------------------------------------------------
// m97-style bf16 GEMM, 128x128 tile, K=512 fixed, BK=32.
// C[m][n] = sum_k A[m][k] * Bt[n][k].
// epi 0: qkv split -> q (bf16, *0.125) / k (fp32) / v (bf16)
// epi 1: fp32 out + bias
// ---------------------------------------------------------------------------
__global__ __launch_bounds__(256) void gemm128(const u16* __restrict__ A,
                                               const u16* __restrict__ Bt,
                                               long aBatch, long bBatch, int epi,
                                               void* __restrict__ o0,
                                               void* __restrict__ o1,
                                               void* __restrict__ o2,
                                               const float* __restrict__ bias) {
  __shared__ u16 As[128 * 32];
  __shared__ u16 Bs[128 * 32];
  const int tid = threadIdx.x;
  const int wid = tid >> 6;
  const int lane = tid & 63;
  const int wm = wid >> 1, wn = wid & 1;
  const int gn = blockIdx.x, gm = blockIdx.y, b = blockIdx.z;

  const u16* Ab = A + aBatch * b + (long)gm * 128 * 512;
  const u16* Bb = Bt + bBatch * b + (long)gn * 128 * 512;

  f32x4 acc[4][4] = {};
  const int q8 = (lane >> 4) * 8;
  const int mr = lane & 15;

  for (int kk = 0; kk < 512; kk += 32) {
    __syncthreads();
#pragma unroll
    for (int i = 0; i < 2; i++) {
      const int slot = i * 256 + tid;
      const int row = slot >> 2;
      const int kc = (slot & 3) * 8;
      gld16((char*)As + i * 4096 + wid * 1024, Ab + (long)row * 512 + kk + kc);
      gld16((char*)Bs + i * 4096 + wid * 1024, Bb + (long)row * 512 + kk + kc);
    }
    __syncthreads();
    bf16x8 af[4], bfv[4];
#pragma unroll
    for (int i = 0; i < 4; i++)
      af[i] = *(const bf16x8*)(As + (wm * 64 + i * 16 + mr) * 32 + q8);
#pragma unroll
    for (int j = 0; j < 4; j++)
      bfv[j] = *(const bf16x8*)(Bs + (wn * 64 + j * 16 + mr) * 32 + q8);
#pragma unroll
    for (int i = 0; i < 4; i++)
#pragma unroll
      for (int j = 0; j < 4; j++)
        acc[i][j] = __builtin_amdgcn_mfma_f32_16x16x32_bf16(af[i], bfv[j], acc[i][j], 0, 0, 0);
  }

  const int col = lane & 15;
  const int quad = lane >> 4;
#pragma unroll
  for (int i = 0; i < 4; i++) {
#pragma unroll
    for (int r = 0; r < 4; r++) {
      const int grow = gm * 128 + wm * 64 + i * 16 + quad * 4 + r;
      if (epi == 1) {
        float* outp = (float*)o0;
        const float bv = bias[grow];
#pragma unroll
        for (int j = 0; j < 4; j++) {
          const long gcol = (long)gn * 128 + wn * 64 + j * 16 + col;
          outp[((long)b * 512 + grow) * 4096 + gcol] = acc[i][j][r] + bv;
        }
      } else if (gm < 4) {           // q third: scale + bf16
        u16* qn = (u16*)o0;
#pragma unroll
        for (int j = 0; j < 4; j++) {
          const long gcol = (long)gn * 128 + wn * 64 + j * 16 + col;
          qn[((long)b * 512 + grow) * 4096 + gcol] = f2b(acc[i][j][r] * 0.125f);
        }
      } else if (gm < 8) {           // k third: fp32 (softmax input precision)
        float* kb = (float*)o1;
#pragma unroll
        for (int j = 0; j < 4; j++) {
          const long gcol = (long)gn * 128 + wn * 64 + j * 16 + col;
          kb[((long)b * 512 + (grow - 512)) * 4096 + gcol] = acc[i][j][r];
        }
      } else {                       // v third: bf16
        u16* vb = (u16*)o2;
#pragma unroll
        for (int j = 0; j < 4; j++) {
          const long gcol = (long)gn * 128 + wn * 64 + j * 16 + col;
          vb[((long)b * 512 + (grow - 1024)) * 4096 + gcol] = f2b(acc[i][j][r]);
        }
      }
    }
  }
}

// ---------------------------------------------------------------------------
// Fused exp(k) row-sum + unnormalized context:
//   ctx[bh][d][e] += sum_n exp(k[d,n]) * v[e,n] ;  rowsum[bh][d] += sum_n exp(k[d,n])
// grid (bh=64, chunk=8), each WG handles 512 n-columns via 8 subtiles of 64.
// (exp without max-subtract is safe: |k| <~ 6 in fp32.)
// ---------------------------------------------------------------------------
__global__ __launch_bounds__(256) void softmax_ctx(const float* __restrict__ kbuf,
                                                   const u16* __restrict__ vbuf,
                                                   float* __restrict__ ctxp,
                                                   float* __restrict__ rsump) {
  __shared__ float et[64 * 68];   // [n][d]
  __shared__ float vt[64 * 68];   // [n][e]
  const int tid = threadIdx.x;
  const int bh = blockIdx.x;
  const int ch = blockIdx.y;
  const float* kp = kbuf + (long)bh * 64 * 4096 + ch * 512;
  const u16* vp = vbuf + (long)bh * 64 * 4096 + ch * 512;

  const int nl = (tid & 15) * 4;
  const int dl = tid >> 4;
  const int d0 = (tid & 15) * 4;
  const int e0 = (tid >> 4) * 4;

  float acc[4][4] = {};
  float rsl[4] = {0.f, 0.f, 0.f, 0.f};

  for (int s = 0; s < 8; s++) {
    __syncthreads();
#pragma unroll
    for (int r = 0; r < 4; r++) {
      const int d = dl + r * 16;
      const float4 kv = *(const float4*)(kp + (long)d * 4096 + s * 64 + nl);
      const float e0v = __expf(kv.x), e1v = __expf(kv.y), e2v = __expf(kv.z), e3v = __expf(kv.w);
      et[(nl + 0) * 68 + d] = e0v;
      et[(nl + 1) * 68 + d] = e1v;
      et[(nl + 2) * 68 + d] = e2v;
      et[(nl + 3) * 68 + d] = e3v;
      rsl[r] += (e0v + e1v) + (e2v + e3v);
      const ushort4 vv = *(const ushort4*)(vp + (long)d * 4096 + s * 64 + nl);
      vt[(nl + 0) * 68 + d] = b2f(vv.x);
      vt[(nl + 1) * 68 + d] = b2f(vv.y);
      vt[(nl + 2) * 68 + d] = b2f(vv.z);
      vt[(nl + 3) * 68 + d] = b2f(vv.w);
    }
    __syncthreads();
#pragma unroll 8
    for (int n = 0; n < 64; n++) {
      const float4 ev = *(const float4*)(et + n * 68 + d0);
      const float4 vv = *(const float4*)(vt + n * 68 + e0);
      const float ea[4] = {ev.x, ev.y, ev.z, ev.w};
      const float va[4] = {vv.x, vv.y, vv.z, vv.w};
#pragma unroll
      for (int a = 0; a < 4; a++)
#pragma unroll
        for (int e = 0; e < 4; e++)
          acc[a][e] += ea[a] * va[e];
    }
  }

#pragma unroll
  for (int r = 0; r < 4; r++) {
    float v = rsl[r];
    v += __shfl_down(v, 8, 16);
    v += __shfl_down(v, 4, 16);
    v += __shfl_down(v, 2, 16);
    v += __shfl_down(v, 1, 16);
    if ((tid & 15) == 0) atomicAdd(rsump + (long)bh * 64 + dl + r * 16, v);
  }
#pragma unroll
  for (int a = 0; a < 4; a++)
#pragma unroll
    for (int e = 0; e < 4; e++)
      atomicAdd(ctxp + (long)bh * 4096 + (d0 + a) * 64 + (e0 + e), acc[a][e]);
}

// ---------------------------------------------------------------------------
// Wc[b][o][h*64+d] = (sum_e w_out[o][h*64+e] * ctx[bh][d][e]) / rowsum[bh][d]
// grid (bh=64, og=4); thread: d = tid&63, 32 consecutive o.
// ---------------------------------------------------------------------------
__global__ __launch_bounds__(256) void wc_kern(const float* __restrict__ ctxp,
                                               const float* __restrict__ rsump,
                                               const float* __restrict__ wout,
                                               u16* __restrict__ Wc) {
  __shared__ float cs[64 * 65];   // [e][d], normalized
  const int tid = threadIdx.x;
  const int bh = blockIdx.x, og = blockIdx.y;
  const int b = bh >> 3, h = bh & 7;
  for (int i = tid; i < 4096; i += 256) {
    const int d = i >> 6, e = i & 63;
    cs[e * 65 + d] = ctxp[(long)bh * 4096 + i] / rsump[(long)bh * 64 + d];
  }
  __syncthreads();
  const int d = tid & 63;
  const int o0 = og * 128 + (tid >> 6) * 32;
  float csr[64];
#pragma unroll
  for (int e = 0; e < 64; e++) csr[e] = cs[e * 65 + d];
  u16* wcp = Wc + (long)b * 512 * 512;
  for (int rr = 0; rr < 32; rr++) {
    const int o = o0 + rr;
    const float* wrow = wout + (long)o * 512 + h * 64;
    float a0 = 0.f, a1 = 0.f, a2 = 0.f, a3 = 0.f;
#pragma unroll
    for (int e = 0; e < 64; e += 4) {
      a0 += wrow[e + 0] * csr[e + 0];
      a1 += wrow[e + 1] * csr[e + 1];
      a2 += wrow[e + 2] * csr[e + 2];
      a3 += wrow[e + 3] * csr[e + 3];
    }
    wcp[(long)o * 512 + h * 64 + d] = f2b((a0 + a1) + (a2 + a3));
  }
}

// ---------------------------------------------------------------------------
// launcher
// ---------------------------------------------------------------------------
extern "C" void kernel_launch(void* const* d_in, const int* in_sizes, int n_in,
                              void* d_out, int out_size, void* d_ws, size_t ws_size,
                              hipStream_t stream) {
  const float* x = (const float*)d_in[0];      // [8][512][4096]
  const float* w_qkv = (const float*)d_in[1];  // [1536][512]
  const float* w_out = (const float*)d_in[2];  // [512][512]
  const float* b_out = (const float*)d_in[3];  // [512]
  float* out = (float*)d_out;                  // [8][512][4096]
  char* ws = (char*)d_ws;

  // workspace layout (bytes); xt region is reused for qt (xt dead after qkv GEMM)
  u16* xt = (u16*)(ws + 0);                    //  32 MB  x^T  bf16 [b][n][i]
  u16* qt = xt;                                //  (alias) q^T bf16 [b][n][hd]
  u16* qnat = (u16*)(ws + 33554432);           //  32 MB  q bf16 [b][hd][n] (scaled)
  float* kbuf = (float*)(ws + 67108864);       //  64 MB  k fp32 [b][c][n]
  u16* vbuf = (u16*)(ws + 134217728);          //  32 MB  v bf16 [b][c][n]
  u16* wqkv = (u16*)(ws + 167772160);          // 1.5 MB  w_qkv bf16
  float* ctx = (float*)(ws + 169345024);       //   1 MB  [bh][d][e] (atomic)
  float* rsum = (float*)(ws + 170393600);      //  16 KB  [bh][d]    (atomic)
  u16* wc = (u16*)(ws + 170409984);            //   4 MB  Wc bf16 [b][o][hd]

  // zero atomic accumulators (ws is poisoned each call); ctx+rsum contiguous
  hipMemsetAsync(ctx, 0, 1048576 + 16384, stream);

  convert_w<<<768, 256, 0, stream>>>(w_qkv, wqkv);
  transpose_to_bf16<0><<<dim3(64, 8, 8), 256, 0, stream>>>(x, xt);

  // qkv = w_qkv @ x  (per batch), split-store q/k/v
  gemm128<<<dim3(32, 12, 8), 256, 0, stream>>>(wqkv, xt, 0L, (long)4096 * 512, 0,
                                               qnat, kbuf, vbuf, nullptr);

  transpose_to_bf16<1><<<dim3(64, 8, 8), 256, 0, stream>>>(qnat, qt);
  softmax_ctx<<<dim3(64, 8), 256, 0, stream>>>(kbuf, vbuf, ctx, rsum);
  wc_kern<<<dim3(64, 4), 256, 0, stream>>>(ctx, rsum, w_out, wc);

  // final = Wc @ q + b_out  (per batch)
  gemm128<<<dim3(32, 4, 8), 256, 0, stream>>>(wc, qt, (long)512 * 512, (long)4096 * 512, 1,
                                              out, nullptr, nullptr, b_out);
}

// Round 2
// 340.096 us; speedup vs baseline: 1.0701x; 1.0701x over previous
//
#include <hip/hip_runtime.h>
#include <hip/hip_bf16.h>
#include <cstdint>

typedef unsigned short u16;
typedef __attribute__((ext_vector_type(8))) short bf16x8;
typedef __attribute__((ext_vector_type(4))) float f32x4;

__device__ __forceinline__ u16 f2b(float f) {
  union { float f; unsigned u; } x; x.f = f;
  unsigned r = x.u + 0x7fffu + ((x.u >> 16) & 1u);   // RNE
  return (u16)(r >> 16);
}
__device__ __forceinline__ void unpk(unsigned u, float& a, float& b) {
  union { unsigned u; float f; } lo, hi;
  lo.u = u << 16; hi.u = u & 0xffff0000u;
  a = lo.f; b = hi.f;
}
__device__ __forceinline__ unsigned pkbf(float a, float b) {
  __hip_bfloat162 h = __float22bfloat162_rn(float2{a, b});
  union { __hip_bfloat162 h; unsigned u; } c; c.h = h;
  return c.u;   // a in low 16, b in high 16
}
__device__ __forceinline__ float el(const float4& v, int c) {
  return ((const float*)&v)[c];
}

__device__ __forceinline__ void gld16(void* lds, const void* g) {
  __builtin_amdgcn_global_load_lds((const __attribute__((address_space(1))) void*)g,
                                   (__attribute__((address_space(3))) void*)lds, 16, 0, 0);
}

// ---------------------------------------------------------------------------
// w_qkv fp32 -> bf16 (same layout)
// ---------------------------------------------------------------------------
__global__ __launch_bounds__(256) void convert_w(const float* __restrict__ w,
                                                 u16* __restrict__ o) {
  const int i = (blockIdx.x * 256 + threadIdx.x) * 4;
  const float4 v = *(const float4*)(w + i);
  ushort4 r;
  r.x = f2b(v.x); r.y = f2b(v.y); r.z = f2b(v.z); r.w = f2b(v.w);
  *(ushort4*)(o + i) = r;
}

// ---------------------------------------------------------------------------
// Fused qkv GEMM: A = w_qkv bf16 [1536][512] (gld16 staging),
// B = x fp32 [b][512][4096] staged+converted+transposed into LDS in-kernel.
// Epilogue: LDS-transpose tile, write qkvt[b][n][1536] bf16 (q scaled 0.125).
// grid (gn=32, gm=12, b=8), 256 threads.
// Bs layout: [128 n][40 u16] rows (80 B, b128-aligned), octet slot XOR-swizzled:
//   k-octet o of row n stored at slot o ^ ((n>>2)&3).
// ---------------------------------------------------------------------------
__global__ __launch_bounds__(256) void qkv_gemm(const u16* __restrict__ wq,
                                                const float* __restrict__ x,
                                                u16* __restrict__ qkvt) {
  __shared__ char smem[18432];
  u16* As = (u16*)smem;            // 128x32 u16, 8 KB
  char* BsB = smem + 8192;         // 128x40 u16, 10.24 KB (byte-addressed)

  const int tid = threadIdx.x;
  const int wid = tid >> 6;
  const int lane = tid & 63;
  const int wm = wid >> 1, wn = wid & 1;
  const int gn = blockIdx.x, gm = blockIdx.y, b = blockIdx.z;
  const int n0 = gn * 128;

  const u16* Ab = wq + (long)gm * 128 * 512;
  const float* xb = x + (long)b * 512 * 4096;

  const int kq = tid >> 5;         // 0..7 : 4 consecutive k rows each
  const int n4 = tid & 31;         // 0..31: 4 consecutive n each
  const int oct = kq >> 1;
  const int khalf = kq & 1;

  f32x4 acc[4][4] = {};
  const int q8 = (lane >> 4) * 8;  // k-octet byte offset/2 for fragments
  const int koct = lane >> 4;
  const int mr = lane & 15;

  float4 bld[4];
  {
    const float* xp = xb + n0 + n4 * 4;
#pragma unroll
    for (int l = 0; l < 4; l++)
      bld[l] = *(const float4*)(xp + (long)(kq * 4 + l) * 4096);
  }

  for (int kk = 0; kk < 512; kk += 32) {
    __syncthreads();
    // A staging (async direct-to-LDS)
#pragma unroll
    for (int i = 0; i < 2; i++) {
      const int slot = i * 256 + tid;
      const int row = slot >> 2;
      const int kc = (slot & 3) * 8;
      gld16((char*)As + i * 4096 + wid * 1024, Ab + (long)row * 512 + kk + kc);
    }
    // B convert + swizzled LDS write
#pragma unroll
    for (int c = 0; c < 4; c++) {
      const int n_l = n4 * 4 + c;
      const unsigned p0 = pkbf(el(bld[0], c), el(bld[1], c));
      const unsigned p1 = pkbf(el(bld[2], c), el(bld[3], c));
      const int slot = oct ^ (n4 & 3);
      uint2 w2; w2.x = p0; w2.y = p1;
      *(uint2*)(BsB + n_l * 80 + slot * 16 + khalf * 8) = w2;
    }
    __syncthreads();
    // prefetch next B tile during MFMA phase
    if (kk + 32 < 512) {
      const float* xp = xb + (long)(kk + 32) * 4096 + n0 + n4 * 4;
#pragma unroll
      for (int l = 0; l < 4; l++)
        bld[l] = *(const float4*)(xp + (long)(kq * 4 + l) * 4096);
    }
    bf16x8 af[4], bfv[4];
#pragma unroll
    for (int i = 0; i < 4; i++)
      af[i] = *(const bf16x8*)(As + (wm * 64 + i * 16 + mr) * 32 + q8);
#pragma unroll
    for (int j = 0; j < 4; j++) {
      const int n_l = wn * 64 + j * 16 + mr;
      const int slot = koct ^ ((n_l >> 2) & 3);
      bfv[j] = *(const bf16x8*)(BsB + n_l * 80 + slot * 16);
    }
#pragma unroll
    for (int i = 0; i < 4; i++)
#pragma unroll
      for (int j = 0; j < 4; j++)
        acc[i][j] = __builtin_amdgcn_mfma_f32_16x16x32_bf16(af[i], bfv[j], acc[i][j], 0, 0, 0);
  }

  // ---- epilogue: transpose to n-major, store qkvt channels [gm*128, +128) ----
  const float sc = (gm < 4) ? 0.125f : 1.0f;
  u16* ts = (u16*)smem;            // 128 n x 72 u16 (144 B rows), 18.4 KB
  const int col = lane & 15;
  const int quad = lane >> 4;
#pragma unroll
  for (int p = 0; p < 2; p++) {
    __syncthreads();
    if (wm == p) {
#pragma unroll
      for (int i = 0; i < 4; i++)
#pragma unroll
        for (int j = 0; j < 4; j++) {
          const int n_l = wn * 64 + j * 16 + col;
          const int o_l = i * 16 + quad * 4;
          ushort4 pk4;
          pk4.x = f2b(acc[i][j][0] * sc);
          pk4.y = f2b(acc[i][j][1] * sc);
          pk4.z = f2b(acc[i][j][2] * sc);
          pk4.w = f2b(acc[i][j][3] * sc);
          *(ushort4*)(ts + n_l * 72 + o_l) = pk4;
        }
    }
    __syncthreads();
    {
      const int n = tid >> 1;
      const int c0 = (tid & 1) * 32;
      u16* dst = qkvt + ((long)b * 4096 + n0 + n) * 1536 + gm * 128 + p * 64;
#pragma unroll
      for (int cc = 0; cc < 4; cc++) {
        const int c = c0 + cc * 8;
        const uint4 v = *(const uint4*)(ts + n * 72 + c);
        *(uint4*)(dst + c) = v;
      }
    }
  }
}

// ---------------------------------------------------------------------------
// softmax + context from n-major qkvt:
//   ctx[bh][d][e] += sum_n exp(k[n][d]) * v[n][e];  rsum[bh][d] += sum_n exp(k[n][d])
// grid (bh=64, chunk=8); block covers 512 n in 8 subtiles of 64.
// ---------------------------------------------------------------------------
__global__ __launch_bounds__(256) void softmax_ctx2(const u16* __restrict__ qkvt,
                                                    float* __restrict__ ctxp,
                                                    float* __restrict__ rsump) {
  __shared__ float ks[64 * 68];   // [n][d] = exp(k)
  __shared__ float vs[64 * 68];   // [n][e]
  const int tid = threadIdx.x;
  const int bh = blockIdx.x;
  const int ch = blockIdx.y;
  const int b = bh >> 3, h = bh & 7;

  const int nr = tid >> 2;        // 0..63
  const int d0t = (tid & 3) * 16; // 16 channel-values per thread per region

  const int d4 = (tid & 15) * 4;
  const int e4 = (tid >> 4) * 4;

  float acc[4][4] = {};
  float rsl = 0.f;

  for (int s = 0; s < 8; s++) {
    __syncthreads();
    const u16* rp = qkvt + ((long)b * 4096 + ch * 512 + s * 64 + nr) * 1536 + h * 64;
    const uint4 kv0 = *(const uint4*)(rp + 512 + d0t);
    const uint4 kv1 = *(const uint4*)(rp + 512 + d0t + 8);
    const uint4 vv0 = *(const uint4*)(rp + 1024 + d0t);
    const uint4 vv1 = *(const uint4*)(rp + 1024 + d0t + 8);
    float f[16];
    unpk(kv0.x, f[0], f[1]);  unpk(kv0.y, f[2], f[3]);
    unpk(kv0.z, f[4], f[5]);  unpk(kv0.w, f[6], f[7]);
    unpk(kv1.x, f[8], f[9]);  unpk(kv1.y, f[10], f[11]);
    unpk(kv1.z, f[12], f[13]); unpk(kv1.w, f[14], f[15]);
#pragma unroll
    for (int m = 0; m < 4; m++) {
      float4 st;
      st.x = __expf(f[m * 4 + 0]); st.y = __expf(f[m * 4 + 1]);
      st.z = __expf(f[m * 4 + 2]); st.w = __expf(f[m * 4 + 3]);
      *(float4*)(ks + nr * 68 + d0t + m * 4) = st;
    }
    unpk(vv0.x, f[0], f[1]);  unpk(vv0.y, f[2], f[3]);
    unpk(vv0.z, f[4], f[5]);  unpk(vv0.w, f[6], f[7]);
    unpk(vv1.x, f[8], f[9]);  unpk(vv1.y, f[10], f[11]);
    unpk(vv1.z, f[12], f[13]); unpk(vv1.w, f[14], f[15]);
#pragma unroll
    for (int m = 0; m < 4; m++) {
      float4 st;
      st.x = f[m * 4 + 0]; st.y = f[m * 4 + 1];
      st.z = f[m * 4 + 2]; st.w = f[m * 4 + 3];
      *(float4*)(vs + nr * 68 + d0t + m * 4) = st;
    }
    __syncthreads();
    if (tid < 64) {
#pragma unroll 8
      for (int n = 0; n < 64; n++) rsl += ks[n * 68 + tid];
    }
#pragma unroll 8
    for (int n = 0; n < 64; n++) {
      const float4 ev = *(const float4*)(ks + n * 68 + d4);
      const float4 vv = *(const float4*)(vs + n * 68 + e4);
      const float ea[4] = {ev.x, ev.y, ev.z, ev.w};
      const float va[4] = {vv.x, vv.y, vv.z, vv.w};
#pragma unroll
      for (int a = 0; a < 4; a++)
#pragma unroll
        for (int e = 0; e < 4; e++)
          acc[a][e] += ea[a] * va[e];
    }
  }

  if (tid < 64) atomicAdd(rsump + (long)bh * 64 + tid, rsl);
#pragma unroll
  for (int a = 0; a < 4; a++)
#pragma unroll
    for (int e = 0; e < 4; e++)
      atomicAdd(ctxp + (long)bh * 4096 + (d4 + a) * 64 + (e4 + e), acc[a][e]);
}

// ---------------------------------------------------------------------------
// Wc[b][o][h*64+d] = (sum_e w_out[o][h*64+e] * ctx[bh][d][e]) / rsum[bh][d]
// ---------------------------------------------------------------------------
__global__ __launch_bounds__(256) void wc_kern(const float* __restrict__ ctxp,
                                               const float* __restrict__ rsump,
                                               const float* __restrict__ wout,
                                               u16* __restrict__ Wc) {
  __shared__ float cs[64 * 65];   // [e][d], normalized
  const int tid = threadIdx.x;
  const int bh = blockIdx.x, og = blockIdx.y;
  const int b = bh >> 3, h = bh & 7;
  for (int i = tid; i < 4096; i += 256) {
    const int d = i >> 6, e = i & 63;
    cs[e * 65 + d] = ctxp[(long)bh * 4096 + i] / rsump[(long)bh * 64 + d];
  }
  __syncthreads();
  const int d = tid & 63;
  const int o0 = og * 128 + (tid >> 6) * 32;
  float csr[64];
#pragma unroll
  for (int e = 0; e < 64; e++) csr[e] = cs[e * 65 + d];
  u16* wcp = Wc + (long)b * 512 * 512;
  for (int rr = 0; rr < 32; rr++) {
    const int o = o0 + rr;
    const float* wrow = wout + (long)o * 512 + h * 64;
    float a0 = 0.f, a1 = 0.f, a2 = 0.f, a3 = 0.f;
#pragma unroll
    for (int e = 0; e < 64; e += 4) {
      a0 += wrow[e + 0] * csr[e + 0];
      a1 += wrow[e + 1] * csr[e + 1];
      a2 += wrow[e + 2] * csr[e + 2];
      a3 += wrow[e + 3] * csr[e + 3];
    }
    wcp[(long)o * 512 + h * 64 + d] = f2b((a0 + a1) + (a2 + a3));
  }
}

// ---------------------------------------------------------------------------
// Final GEMM: out[b][o][n] = sum_ch Wc[b][o][ch] * qkvt[b][n][ch] + bias[o]
// A = Wc (stride 512), B = qkvt channels [0,512) (stride 1536). m97 structure.
// grid (gn=32, gm=4, b=8)
// ---------------------------------------------------------------------------
__global__ __launch_bounds__(256) void out_gemm(const u16* __restrict__ Wc,
                                                const u16* __restrict__ qkvt,
                                                const float* __restrict__ bias,
                                                float* __restrict__ outp) {
  __shared__ u16 As[128 * 32];
  __shared__ u16 Bs[128 * 32];
  const int tid = threadIdx.x;
  const int wid = tid >> 6;
  const int lane = tid & 63;
  const int wm = wid >> 1, wn = wid & 1;
  const int gn = blockIdx.x, gm = blockIdx.y, b = blockIdx.z;

  const u16* Ab = Wc + (long)b * 512 * 512 + (long)gm * 128 * 512;
  const u16* Bb = qkvt + ((long)b * 4096 + (long)gn * 128) * 1536;

  f32x4 acc[4][4] = {};
  const int q8 = (lane >> 4) * 8;
  const int mr = lane & 15;

  for (int kk = 0; kk < 512; kk += 32) {
    __syncthreads();
#pragma unroll
    for (int i = 0; i < 2; i++) {
      const int slot = i * 256 + tid;
      const int row = slot >> 2;
      const int kc = (slot & 3) * 8;
      gld16((char*)As + i * 4096 + wid * 1024, Ab + (long)row * 512 + kk + kc);
      gld16((char*)Bs + i * 4096 + wid * 1024, Bb + (long)row * 1536 + kk + kc);
    }
    __syncthreads();
    bf16x8 af[4], bfv[4];
#pragma unroll
    for (int i = 0; i < 4; i++)
      af[i] = *(const bf16x8*)(As + (wm * 64 + i * 16 + mr) * 32 + q8);
#pragma unroll
    for (int j = 0; j < 4; j++)
      bfv[j] = *(const bf16x8*)(Bs + (wn * 64 + j * 16 + mr) * 32 + q8);
#pragma unroll
    for (int i = 0; i < 4; i++)
#pragma unroll
      for (int j = 0; j < 4; j++)
        acc[i][j] = __builtin_amdgcn_mfma_f32_16x16x32_bf16(af[i], bfv[j], acc[i][j], 0, 0, 0);
  }

  const int col = lane & 15;
  const int quad = lane >> 4;
#pragma unroll
  for (int i = 0; i < 4; i++) {
#pragma unroll
    for (int r = 0; r < 4; r++) {
      const int grow = gm * 128 + wm * 64 + i * 16 + quad * 4 + r;
      const float bv = bias[grow];
#pragma unroll
      for (int j = 0; j < 4; j++) {
        const long gcol = (long)gn * 128 + wn * 64 + j * 16 + col;
        outp[((long)b * 512 + grow) * 4096 + gcol] = acc[i][j][r] + bv;
      }
    }
  }
}

// ---------------------------------------------------------------------------
// launcher
// ---------------------------------------------------------------------------
extern "C" void kernel_launch(void* const* d_in, const int* in_sizes, int n_in,
                              void* d_out, int out_size, void* d_ws, size_t ws_size,
                              hipStream_t stream) {
  const float* x = (const float*)d_in[0];      // [8][512][4096]
  const float* w_qkv = (const float*)d_in[1];  // [1536][512]
  const float* w_out = (const float*)d_in[2];  // [512][512]
  const float* b_out = (const float*)d_in[3];  // [512]
  float* out = (float*)d_out;                  // [8][512][4096]
  char* ws = (char*)d_ws;

  // workspace layout (bytes)
  u16* qkvt = (u16*)(ws + 0);                  // 96 MB  [b][n][1536] bf16
  u16* wqkv = (u16*)(ws + 100663296);          // 1.5 MB w_qkv bf16
  u16* wc = (u16*)(ws + 102236160);            //  4 MB  Wc bf16 [b][o][hd]
  float* ctx = (float*)(ws + 106430464);       //  1 MB  [bh][d][e] (atomic)
  float* rsum = (float*)(ws + 107479040);      // 16 KB  [bh][d]    (atomic)

  hipMemsetAsync(ctx, 0, 1048576 + 16384, stream);

  convert_w<<<768, 256, 0, stream>>>(w_qkv, wqkv);
  qkv_gemm<<<dim3(32, 12, 8), 256, 0, stream>>>(wqkv, x, qkvt);
  softmax_ctx2<<<dim3(64, 8), 256, 0, stream>>>(qkvt, ctx, rsum);
  wc_kern<<<dim3(64, 4), 256, 0, stream>>>(ctx, rsum, w_out, wc);
  out_gemm<<<dim3(32, 4, 8), 256, 0, stream>>>(wc, qkvt, b_out, out);
}

// Round 3
// 336.627 us; speedup vs baseline: 1.0811x; 1.0103x over previous
//
#include <hip/hip_runtime.h>
#include <hip/hip_bf16.h>
#include <cstdint>

typedef unsigned short u16;
typedef __attribute__((ext_vector_type(8))) short bf16x8;
typedef __attribute__((ext_vector_type(4))) float f32x4;

__device__ __forceinline__ u16 f2b(float f) {
  union { float f; unsigned u; } x; x.f = f;
  unsigned r = x.u + 0x7fffu + ((x.u >> 16) & 1u);   // RNE
  return (u16)(r >> 16);
}
__device__ __forceinline__ void unpk(unsigned u, float& a, float& b) {
  union { unsigned u; float f; } lo, hi;
  lo.u = u << 16; hi.u = u & 0xffff0000u;
  a = lo.f; b = hi.f;
}
__device__ __forceinline__ unsigned pkbf(float a, float b) {
  __hip_bfloat162 h = __float22bfloat162_rn(float2{a, b});
  union { __hip_bfloat162 h; unsigned u; } c; c.h = h;
  return c.u;   // a low 16, b high 16
}
__device__ __forceinline__ float el(const float4& v, int c) {
  return ((const float*)&v)[c];
}
__device__ __forceinline__ void gld16(void* lds, const void* g) {
  __builtin_amdgcn_global_load_lds((const __attribute__((address_space(1))) void*)g,
                                   (__attribute__((address_space(3))) void*)lds, 16, 0, 0);
}
__device__ __forceinline__ int sw_idx(int n, int c) {
  return n * 64 + ((((c >> 2) ^ (n >> 2)) & 15) << 2) + (c & 3);
}

// ---------------------------------------------------------------------------
// prep: (a) blk<512: convert w_qkv rows 512..1535 -> wkv bf16 [1024][512]
//       (b) blk<576: transpose-convert w_qkv rows 0..511 -> wqT bf16 [i][ch]
//       (c) else:    zero ctx+rsum (266240 floats)
// ---------------------------------------------------------------------------
__global__ __launch_bounds__(256) void prep(const float* __restrict__ w_qkv,
                                            u16* __restrict__ wkv,
                                            u16* __restrict__ wqT,
                                            float* __restrict__ zbuf) {
  const int tid = threadIdx.x;
  const int blk = blockIdx.x;
  if (blk < 512) {
    const int i = blk * 1024 + tid * 4;
    const float4 v = *(const float4*)(w_qkv + 262144 + i);
    ushort4 r; r.x = f2b(v.x); r.y = f2b(v.y); r.z = f2b(v.z); r.w = f2b(v.w);
    *(ushort4*)(wkv + i) = r;
  } else if (blk < 576) {
    __shared__ u16 t[4096];
    const int bb = blk - 512;
    const int i0 = (bb & 7) * 64;   // output-row (i) block
    const int c0 = (bb >> 3) * 64;  // input-row (ch) block
    const int il = (tid & 15) * 4;
    const int cl = tid >> 4;
#pragma unroll
    for (int r = 0; r < 4; r++) {
      const int c = cl + r * 16;
      const float4 v = *(const float4*)(w_qkv + (c0 + c) * 512 + i0 + il);
      t[sw_idx(il + 0, c)] = f2b(v.x);
      t[sw_idx(il + 1, c)] = f2b(v.y);
      t[sw_idx(il + 2, c)] = f2b(v.z);
      t[sw_idx(il + 3, c)] = f2b(v.w);
    }
    __syncthreads();
    const int cw = (tid & 15) * 4;
#pragma unroll
    for (int r = 0; r < 4; r++) {
      const int i = cl + r * 16;
      const u16* tp = &t[sw_idx(i, cw)];
      ushort4 o; o.x = tp[0]; o.y = tp[1]; o.z = tp[2]; o.w = tp[3];
      *(ushort4*)(wqT + (i0 + i) * 512 + c0 + cw) = o;
    }
  } else {
    const int zi = (blk - 576) * 1024 + tid * 4;
    if (zi < 266240) *(float4*)(zbuf + zi) = float4{0.f, 0.f, 0.f, 0.f};
  }
}

// ---------------------------------------------------------------------------
// kv_gemm: A = wkv bf16 [1024][512] (gld16), B = x fp32 (fused cvt+transpose
// into LDS; 144-B rows, slot = oct ^ ((n>>3)&3) -> 2-way max on r/w).
// Epilogue: LDS transpose, store kvt[b][n][1024] bf16. grid (32, 8, 8).
// ---------------------------------------------------------------------------
__global__ __launch_bounds__(256) void kv_gemm(const u16* __restrict__ wkv,
                                               const float* __restrict__ x,
                                               u16* __restrict__ kvt) {
  __shared__ char smem[26624];
  u16* As = (u16*)smem;            // 128x32 u16 (8 KB)
  char* BsB = smem + 8192;         // 128 rows x 144 B (18.4 KB)

  const int tid = threadIdx.x;
  const int wid = tid >> 6;
  const int lane = tid & 63;
  const int wm = wid >> 1, wn = wid & 1;
  const int gn = blockIdx.x, gm = blockIdx.y, b = blockIdx.z;
  const int n0 = gn * 128;

  const u16* Ab = wkv + (long)gm * 128 * 512;
  const float* xb = x + (long)b * 512 * 4096;

  const int kq = tid >> 5;         // 0..7
  const int n4 = tid & 31;         // 0..31
  const int oct = kq >> 1;
  const int khalf = kq & 1;

  f32x4 acc[4][4] = {};
  const int q8 = (lane >> 4) * 8;
  const int koct = lane >> 4;
  const int mr = lane & 15;

  float4 bld[4];
  {
    const float* xp = xb + n0 + n4 * 4;
#pragma unroll
    for (int l = 0; l < 4; l++)
      bld[l] = *(const float4*)(xp + (long)(kq * 4 + l) * 4096);
  }

  for (int kk = 0; kk < 512; kk += 32) {
    __syncthreads();
#pragma unroll
    for (int i = 0; i < 2; i++) {
      const int slot = i * 256 + tid;
      const int row = slot >> 2;
      const int kc = (slot & 3) * 8;
      gld16((char*)As + i * 4096 + wid * 1024, Ab + (long)row * 512 + kk + kc);
    }
#pragma unroll
    for (int c = 0; c < 4; c++) {
      const int n_l = n4 * 4 + c;
      const unsigned p0 = pkbf(el(bld[0], c), el(bld[1], c));
      const unsigned p1 = pkbf(el(bld[2], c), el(bld[3], c));
      const int slot = oct ^ ((n_l >> 3) & 3);
      uint2 w2; w2.x = p0; w2.y = p1;
      *(uint2*)(BsB + n_l * 144 + slot * 16 + khalf * 8) = w2;
    }
    __syncthreads();
    if (kk + 32 < 512) {
      const float* xp = xb + (long)(kk + 32) * 4096 + n0 + n4 * 4;
#pragma unroll
      for (int l = 0; l < 4; l++)
        bld[l] = *(const float4*)(xp + (long)(kq * 4 + l) * 4096);
    }
    bf16x8 af[4], bfv[4];
#pragma unroll
    for (int i = 0; i < 4; i++)
      af[i] = *(const bf16x8*)(As + (wm * 64 + i * 16 + mr) * 32 + q8);
#pragma unroll
    for (int j = 0; j < 4; j++) {
      const int n_l = wn * 64 + j * 16 + mr;
      const int slot = koct ^ ((n_l >> 3) & 3);
      bfv[j] = *(const bf16x8*)(BsB + n_l * 144 + slot * 16);
    }
#pragma unroll
    for (int i = 0; i < 4; i++)
#pragma unroll
      for (int j = 0; j < 4; j++)
        acc[i][j] = __builtin_amdgcn_mfma_f32_16x16x32_bf16(af[i], bfv[j], acc[i][j], 0, 0, 0);
  }

  // epilogue: transpose tile to n-major, channels [gm*128, +128) of kvt
  u16* ts = (u16*)smem;            // 128 n x 72 u16
  const int col = lane & 15;
  const int quad = lane >> 4;
#pragma unroll
  for (int p = 0; p < 2; p++) {
    __syncthreads();
    if (wm == p) {
#pragma unroll
      for (int i = 0; i < 4; i++)
#pragma unroll
        for (int j = 0; j < 4; j++) {
          const int n_l = wn * 64 + j * 16 + col;
          const int o_l = i * 16 + quad * 4;
          ushort4 pk4;
          pk4.x = f2b(acc[i][j][0]);
          pk4.y = f2b(acc[i][j][1]);
          pk4.z = f2b(acc[i][j][2]);
          pk4.w = f2b(acc[i][j][3]);
          *(ushort4*)(ts + n_l * 72 + o_l) = pk4;
        }
    }
    __syncthreads();
    {
      const int n = tid >> 1;
      const int c0 = (tid & 1) * 32;
      u16* dst = kvt + ((long)b * 4096 + n0 + n) * 1024 + gm * 128 + p * 64;
#pragma unroll
      for (int cc = 0; cc < 4; cc++) {
        const int c = c0 + cc * 8;
        const uint4 v = *(const uint4*)(ts + n * 72 + c);
        *(uint4*)(dst + c) = v;
      }
    }
  }
}

// ---------------------------------------------------------------------------
// softmax + context from n-major kvt[b][n][1024] (k: 0..511, v: 512..1023):
//   ctx[bh][d][e] += sum_n exp(k[n][d]) * v[n][e];  rsum[bh][d] += exp sums
// grid (bh=64, chunk=8).
// ---------------------------------------------------------------------------
__global__ __launch_bounds__(256) void softmax_ctx2(const u16* __restrict__ kvt,
                                                    float* __restrict__ ctxp,
                                                    float* __restrict__ rsump) {
  __shared__ float ks[64 * 68];
  __shared__ float vs[64 * 68];
  const int tid = threadIdx.x;
  const int bh = blockIdx.x;
  const int ch = blockIdx.y;
  const int b = bh >> 3, h = bh & 7;

  const int nr = tid >> 2;
  const int d0t = (tid & 3) * 16;

  const int d4 = (tid & 15) * 4;
  const int e4 = (tid >> 4) * 4;

  float acc[4][4] = {};
  float rsl = 0.f;

  for (int s = 0; s < 8; s++) {
    __syncthreads();
    const u16* rp = kvt + ((long)b * 4096 + ch * 512 + s * 64 + nr) * 1024 + h * 64;
    const uint4 kv0 = *(const uint4*)(rp + d0t);
    const uint4 kv1 = *(const uint4*)(rp + d0t + 8);
    const uint4 vv0 = *(const uint4*)(rp + 512 + d0t);
    const uint4 vv1 = *(const uint4*)(rp + 512 + d0t + 8);
    float f[16];
    unpk(kv0.x, f[0], f[1]);   unpk(kv0.y, f[2], f[3]);
    unpk(kv0.z, f[4], f[5]);   unpk(kv0.w, f[6], f[7]);
    unpk(kv1.x, f[8], f[9]);   unpk(kv1.y, f[10], f[11]);
    unpk(kv1.z, f[12], f[13]); unpk(kv1.w, f[14], f[15]);
#pragma unroll
    for (int m = 0; m < 4; m++) {
      float4 st;
      st.x = __expf(f[m * 4 + 0]); st.y = __expf(f[m * 4 + 1]);
      st.z = __expf(f[m * 4 + 2]); st.w = __expf(f[m * 4 + 3]);
      *(float4*)(ks + nr * 68 + d0t + m * 4) = st;
    }
    unpk(vv0.x, f[0], f[1]);   unpk(vv0.y, f[2], f[3]);
    unpk(vv0.z, f[4], f[5]);   unpk(vv0.w, f[6], f[7]);
    unpk(vv1.x, f[8], f[9]);   unpk(vv1.y, f[10], f[11]);
    unpk(vv1.z, f[12], f[13]); unpk(vv1.w, f[14], f[15]);
#pragma unroll
    for (int m = 0; m < 4; m++) {
      float4 st;
      st.x = f[m * 4 + 0]; st.y = f[m * 4 + 1];
      st.z = f[m * 4 + 2]; st.w = f[m * 4 + 3];
      *(float4*)(vs + nr * 68 + d0t + m * 4) = st;
    }
    __syncthreads();
    if (tid < 64) {
#pragma unroll 8
      for (int n = 0; n < 64; n++) rsl += ks[n * 68 + tid];
    }
#pragma unroll 8
    for (int n = 0; n < 64; n++) {
      const float4 ev = *(const float4*)(ks + n * 68 + d4);
      const float4 vv = *(const float4*)(vs + n * 68 + e4);
      const float ea[4] = {ev.x, ev.y, ev.z, ev.w};
      const float va[4] = {vv.x, vv.y, vv.z, vv.w};
#pragma unroll
      for (int a = 0; a < 4; a++)
#pragma unroll
        for (int e = 0; e < 4; e++)
          acc[a][e] += ea[a] * va[e];
    }
  }

  if (tid < 64) atomicAdd(rsump + (long)bh * 64 + tid, rsl);
#pragma unroll
  for (int a = 0; a < 4; a++)
#pragma unroll
    for (int e = 0; e < 4; e++)
      atomicAdd(ctxp + (long)bh * 4096 + (d4 + a) * 64 + (e4 + e), acc[a][e]);
}

// ---------------------------------------------------------------------------
// Wc[b][o][h*64+d] = (sum_e w_out[o][h*64+e] * ctx[bh][d][e]) / rsum[bh][d]
// ---------------------------------------------------------------------------
__global__ __launch_bounds__(256) void wc_kern(const float* __restrict__ ctxp,
                                               const float* __restrict__ rsump,
                                               const float* __restrict__ wout,
                                               u16* __restrict__ Wc) {
  __shared__ float cs[64 * 65];
  const int tid = threadIdx.x;
  const int bh = blockIdx.x, og = blockIdx.y;
  const int b = bh >> 3, h = bh & 7;
  for (int i = tid; i < 4096; i += 256) {
    const int d = i >> 6, e = i & 63;
    cs[e * 65 + d] = ctxp[(long)bh * 4096 + i] / rsump[(long)bh * 64 + d];
  }
  __syncthreads();
  const int d = tid & 63;
  const int o0 = og * 128 + (tid >> 6) * 32;
  float csr[64];
#pragma unroll
  for (int e = 0; e < 64; e++) csr[e] = cs[e * 65 + d];
  u16* wcp = Wc + (long)b * 512 * 512;
  for (int rr = 0; rr < 32; rr++) {
    const int o = o0 + rr;
    const float* wrow = wout + (long)o * 512 + h * 64;
    float a0 = 0.f, a1 = 0.f, a2 = 0.f, a3 = 0.f;
#pragma unroll
    for (int e = 0; e < 64; e += 4) {
      a0 += wrow[e + 0] * csr[e + 0];
      a1 += wrow[e + 1] * csr[e + 1];
      a2 += wrow[e + 2] * csr[e + 2];
      a3 += wrow[e + 3] * csr[e + 3];
    }
    wcp[(long)o * 512 + h * 64 + d] = f2b((a0 + a1) + (a2 + a3));
  }
}

// ---------------------------------------------------------------------------
// Weff[b][o][i] = 0.125 * sum_ch Wc[b][o][ch] * wqT[i][ch].  grid (4, 4, 8).
// ---------------------------------------------------------------------------
__global__ __launch_bounds__(256) void weff_gemm(const u16* __restrict__ Wc,
                                                 const u16* __restrict__ wqT,
                                                 u16* __restrict__ Weff) {
  __shared__ u16 As[128 * 32];
  __shared__ u16 Bs[128 * 32];
  const int tid = threadIdx.x;
  const int wid = tid >> 6;
  const int lane = tid & 63;
  const int wm = wid >> 1, wn = wid & 1;
  const int gn = blockIdx.x, gm = blockIdx.y, b = blockIdx.z;

  const u16* Ab = Wc + (long)b * 512 * 512 + (long)gm * 128 * 512;
  const u16* Bb = wqT + (long)gn * 128 * 512;

  f32x4 acc[4][4] = {};
  const int q8 = (lane >> 4) * 8;
  const int mr = lane & 15;

  for (int kk = 0; kk < 512; kk += 32) {
    __syncthreads();
#pragma unroll
    for (int i = 0; i < 2; i++) {
      const int slot = i * 256 + tid;
      const int row = slot >> 2;
      const int kc = (slot & 3) * 8;
      gld16((char*)As + i * 4096 + wid * 1024, Ab + (long)row * 512 + kk + kc);
      gld16((char*)Bs + i * 4096 + wid * 1024, Bb + (long)row * 512 + kk + kc);
    }
    __syncthreads();
    bf16x8 af[4], bfv[4];
#pragma unroll
    for (int i = 0; i < 4; i++)
      af[i] = *(const bf16x8*)(As + (wm * 64 + i * 16 + mr) * 32 + q8);
#pragma unroll
    for (int j = 0; j < 4; j++)
      bfv[j] = *(const bf16x8*)(Bs + (wn * 64 + j * 16 + mr) * 32 + q8);
#pragma unroll
    for (int i = 0; i < 4; i++)
#pragma unroll
      for (int j = 0; j < 4; j++)
        acc[i][j] = __builtin_amdgcn_mfma_f32_16x16x32_bf16(af[i], bfv[j], acc[i][j], 0, 0, 0);
  }

  const int col = lane & 15;
  const int quad = lane >> 4;
  u16* wb = Weff + (long)b * 512 * 512;
#pragma unroll
  for (int i = 0; i < 4; i++)
#pragma unroll
    for (int r = 0; r < 4; r++) {
      const int grow = gm * 128 + wm * 64 + i * 16 + quad * 4 + r;
#pragma unroll
      for (int j = 0; j < 4; j++) {
        const int gcol = gn * 128 + wn * 64 + j * 16 + col;
        wb[(long)grow * 512 + gcol] = f2b(acc[i][j][r] * 0.125f);
      }
    }
}

// ---------------------------------------------------------------------------
// out_gemm: out[b][o][n] = sum_i Weff[b][o][i] * x[b][i][n] + bias[o]
// A = Weff bf16 (gld16), B = x fp32 (fused cvt into swizzled LDS).
// grid (32, 4, 8).
// ---------------------------------------------------------------------------
__global__ __launch_bounds__(256) void out_gemm(const u16* __restrict__ Weff,
                                                const float* __restrict__ x,
                                                const float* __restrict__ bias,
                                                float* __restrict__ outp) {
  __shared__ char smem[26624];
  u16* As = (u16*)smem;
  char* BsB = smem + 8192;

  const int tid = threadIdx.x;
  const int wid = tid >> 6;
  const int lane = tid & 63;
  const int wm = wid >> 1, wn = wid & 1;
  const int gn = blockIdx.x, gm = blockIdx.y, b = blockIdx.z;
  const int n0 = gn * 128;

  const u16* Ab = Weff + (long)b * 512 * 512 + (long)gm * 128 * 512;
  const float* xb = x + (long)b * 512 * 4096;

  const int kq = tid >> 5;
  const int n4 = tid & 31;
  const int oct = kq >> 1;
  const int khalf = kq & 1;

  f32x4 acc[4][4] = {};
  const int q8 = (lane >> 4) * 8;
  const int koct = lane >> 4;
  const int mr = lane & 15;

  float4 bld[4];
  {
    const float* xp = xb + n0 + n4 * 4;
#pragma unroll
    for (int l = 0; l < 4; l++)
      bld[l] = *(const float4*)(xp + (long)(kq * 4 + l) * 4096);
  }

  for (int kk = 0; kk < 512; kk += 32) {
    __syncthreads();
#pragma unroll
    for (int i = 0; i < 2; i++) {
      const int slot = i * 256 + tid;
      const int row = slot >> 2;
      const int kc = (slot & 3) * 8;
      gld16((char*)As + i * 4096 + wid * 1024, Ab + (long)row * 512 + kk + kc);
    }
#pragma unroll
    for (int c = 0; c < 4; c++) {
      const int n_l = n4 * 4 + c;
      const unsigned p0 = pkbf(el(bld[0], c), el(bld[1], c));
      const unsigned p1 = pkbf(el(bld[2], c), el(bld[3], c));
      const int slot = oct ^ ((n_l >> 3) & 3);
      uint2 w2; w2.x = p0; w2.y = p1;
      *(uint2*)(BsB + n_l * 144 + slot * 16 + khalf * 8) = w2;
    }
    __syncthreads();
    if (kk + 32 < 512) {
      const float* xp = xb + (long)(kk + 32) * 4096 + n0 + n4 * 4;
#pragma unroll
      for (int l = 0; l < 4; l++)
        bld[l] = *(const float4*)(xp + (long)(kq * 4 + l) * 4096);
    }
    bf16x8 af[4], bfv[4];
#pragma unroll
    for (int i = 0; i < 4; i++)
      af[i] = *(const bf16x8*)(As + (wm * 64 + i * 16 + mr) * 32 + q8);
#pragma unroll
    for (int j = 0; j < 4; j++) {
      const int n_l = wn * 64 + j * 16 + mr;
      const int slot = koct ^ ((n_l >> 3) & 3);
      bfv[j] = *(const bf16x8*)(BsB + n_l * 144 + slot * 16);
    }
#pragma unroll
    for (int i = 0; i < 4; i++)
#pragma unroll
      for (int j = 0; j < 4; j++)
        acc[i][j] = __builtin_amdgcn_mfma_f32_16x16x32_bf16(af[i], bfv[j], acc[i][j], 0, 0, 0);
  }

  const int col = lane & 15;
  const int quad = lane >> 4;
#pragma unroll
  for (int i = 0; i < 4; i++)
#pragma unroll
    for (int r = 0; r < 4; r++) {
      const int grow = gm * 128 + wm * 64 + i * 16 + quad * 4 + r;
      const float bv = bias[grow];
#pragma unroll
      for (int j = 0; j < 4; j++) {
        const long gcol = (long)n0 + wn * 64 + j * 16 + col;
        outp[((long)b * 512 + grow) * 4096 + gcol] = acc[i][j][r] + bv;
      }
    }
}

// ---------------------------------------------------------------------------
// launcher
// ---------------------------------------------------------------------------
extern "C" void kernel_launch(void* const* d_in, const int* in_sizes, int n_in,
                              void* d_out, int out_size, void* d_ws, size_t ws_size,
                              hipStream_t stream) {
  const float* x = (const float*)d_in[0];      // [8][512][4096]
  const float* w_qkv = (const float*)d_in[1];  // [1536][512]
  const float* w_out = (const float*)d_in[2];  // [512][512]
  const float* b_out = (const float*)d_in[3];  // [512]
  float* out = (float*)d_out;                  // [8][512][4096]
  char* ws = (char*)d_ws;

  u16* kvt = (u16*)(ws + 0);                   // 64 MB  [b][n][1024] bf16
  u16* wkv = (u16*)(ws + 67108864);            //  1 MB  w_qkv rows 512..1535 bf16
  u16* wqT = (u16*)(ws + 68157440);            // .5 MB  Wq^T bf16 [i][ch]
  u16* wc = (u16*)(ws + 68681728);             //  4 MB  Wc bf16 [b][o][ch]
  u16* weff = (u16*)(ws + 72876032);           //  4 MB  Weff bf16 [b][o][i]
  float* ctx = (float*)(ws + 77070336);        //  1 MB  [bh][d][e] (atomic)
  float* rsum = (float*)(ws + 78118912);       // 16 KB  [bh][d]    (atomic)

  prep<<<836, 256, 0, stream>>>(w_qkv, wkv, wqT, ctx);
  kv_gemm<<<dim3(32, 8, 8), 256, 0, stream>>>(wkv, x, kvt);
  softmax_ctx2<<<dim3(64, 8), 256, 0, stream>>>(kvt, ctx, rsum);
  wc_kern<<<dim3(64, 4), 256, 0, stream>>>(ctx, rsum, w_out, wc);
  weff_gemm<<<dim3(4, 4, 8), 256, 0, stream>>>(wc, wqT, weff);
  out_gemm<<<dim3(32, 4, 8), 256, 0, stream>>>(weff, x, b_out, out);
}